// Round 14
// baseline (77.258 us; speedup 1.0000x reference)
//
#include <hip/hip_runtime.h>

// Hausdorff adv2ori via MFMA: B=8, K=8192.
// dist(n,m) = oo_n + aa_m - 2*o.a ; C = mfma(A',B') = oo_n - 2*o.a (fp16 hi/lo split)
// loss = mean_b( w_b * max_m min_n dist )
//
// R13 post-mortem: pinned-reg tile asm -> 74.7us (best). Residual main ~29us;
// R9 warm-rep evidence (18.7/rep vs ~33 single-shot) says part of the gap is
// the post-fill cold window (uncontrollable). Remaining controllable cost:
// 2x s_nop7 per tile (16cyc/wave, ~9% of issue) + serial fold->MFMA ordering.
// R14: dual-bank pipelined tile asm. Banks X=v64..95 (d0,d1), Y=v96..127
// (d2,d3). Steady state: {foldX(t-1), MFMA2->X(t), foldY(t-1), MFMA2->Y(t)} —
// every MFMA's first reader is >=18 instrs (>=36 cyc) later -> ZERO s_nops in
// the loop (prologue keeps one pair); matrix pipe fed during folds. WAR
// (MFMA rewriting just-folded bank) is in-order-safe. Frame (staging, grid,
// launch_bounds(256,4), reduceB) = R13 proven.

#define KPTS 8192
#define BATCH 8
#define NSPLIT 8
#define RBLK (KPTS / NSPLIT)          // 1024 rows per slice
#define TSLICE (RBLK / 32)            // 32 MFMA row-tiles per slice
#define CBLK 512                      // adv columns per block (4 waves x 128)
#define MCHUNK (KPTS / CBLK)          // 16

typedef _Float16 half8 __attribute__((ext_vector_type(8)));

#define CLOB_X "v64","v65","v66","v67","v68","v69","v70","v71",               \
               "v72","v73","v74","v75","v76","v77","v78","v79",               \
               "v80","v81","v82","v83","v84","v85","v86","v87",               \
               "v88","v89","v90","v91","v92","v93","v94","v95"
#define CLOB_Y "v96","v97","v98","v99","v100","v101","v102","v103",           \
               "v104","v105","v106","v107","v108","v109","v110","v111",       \
               "v112","v113","v114","v115","v116","v117","v118","v119",       \
               "v120","v121","v122","v123","v124","v125","v126","v127"

// Two MFMAs into bank X (d0->v64:79, d1->v80:95), C = inline 0.
#define MFMA2_X(af_, b0_, b1_)                                                \
    asm volatile(                                                             \
        "v_mfma_f32_32x32x16_f16 v[64:79], %0, %1, 0\n\t"                     \
        "v_mfma_f32_32x32x16_f16 v[80:95], %0, %2, 0"                         \
        :: "v"(af_), "v"(b0_), "v"(b1_) : CLOB_X)

// Two MFMAs into bank Y (d2->v96:111, d3->v112:127).
#define MFMA2_Y(af_, b2_, b3_)                                                \
    asm volatile(                                                             \
        "v_mfma_f32_32x32x16_f16 v[96:111], %0, %1, 0\n\t"                    \
        "v_mfma_f32_32x32x16_f16 v[112:127], %0, %2, 0"                       \
        :: "v"(af_), "v"(b2_), "v"(b3_) : CLOB_Y)

// In-place min3 fold of bank X into rm0, rm1 (16 instrs).
#define FOLD_X(rm0_, rm1_)                                                    \
    asm volatile(                                                             \
        "v_min3_f32 v64, v64, v65, v66\n\t"                                   \
        "v_min3_f32 v67, v67, v68, v69\n\t"                                   \
        "v_min3_f32 v70, v70, v71, v72\n\t"                                   \
        "v_min3_f32 v73, v73, v74, v75\n\t"                                   \
        "v_min3_f32 v76, v76, v77, v78\n\t"                                   \
        "v_min3_f32 v79, v79, %0, v64\n\t"                                    \
        "v_min3_f32 v67, v67, v70, v73\n\t"                                   \
        "v_min3_f32 %0, v76, v79, v67\n\t"                                    \
        "v_min3_f32 v80, v80, v81, v82\n\t"                                   \
        "v_min3_f32 v83, v83, v84, v85\n\t"                                   \
        "v_min3_f32 v86, v86, v87, v88\n\t"                                   \
        "v_min3_f32 v89, v89, v90, v91\n\t"                                   \
        "v_min3_f32 v92, v92, v93, v94\n\t"                                   \
        "v_min3_f32 v95, v95, %1, v80\n\t"                                    \
        "v_min3_f32 v83, v83, v86, v89\n\t"                                   \
        "v_min3_f32 %1, v92, v95, v83"                                        \
        : "+v"(rm0_), "+v"(rm1_) :: CLOB_X)

// In-place min3 fold of bank Y into rm2, rm3 (16 instrs).
#define FOLD_Y(rm2_, rm3_)                                                    \
    asm volatile(                                                             \
        "v_min3_f32 v96, v96, v97, v98\n\t"                                   \
        "v_min3_f32 v99, v99, v100, v101\n\t"                                 \
        "v_min3_f32 v102, v102, v103, v104\n\t"                               \
        "v_min3_f32 v105, v105, v106, v107\n\t"                               \
        "v_min3_f32 v108, v108, v109, v110\n\t"                               \
        "v_min3_f32 v111, v111, %0, v96\n\t"                                  \
        "v_min3_f32 v99, v99, v102, v105\n\t"                                 \
        "v_min3_f32 %0, v108, v111, v99\n\t"                                  \
        "v_min3_f32 v112, v112, v113, v114\n\t"                               \
        "v_min3_f32 v115, v115, v116, v117\n\t"                               \
        "v_min3_f32 v118, v118, v119, v120\n\t"                               \
        "v_min3_f32 v121, v121, v122, v123\n\t"                               \
        "v_min3_f32 v124, v124, v125, v126\n\t"                               \
        "v_min3_f32 v127, v127, %1, v112\n\t"                                 \
        "v_min3_f32 v115, v115, v118, v121\n\t"                               \
        "v_min3_f32 %1, v124, v127, v115"                                     \
        : "+v"(rm2_), "+v"(rm3_) :: CLOB_Y)

__global__ __launch_bounds__(256, 4) void hausdorff(const float* __restrict__ adv,
                                                    const float* __restrict__ ori,
                                                    float* __restrict__ part,
                                                    float* __restrict__ out) {
    // Tile-planar A' slice: tile t at halfs [t*512,(t+1)*512); lane reads
    // byte lane*16 -> linear, conflict-free. +1 pad tile for last prefetch.
    __shared__ _Float16 sA[(TSLICE + 1) * 512];   // 33 KB -> 4 blocks/CU

    const int bid  = blockIdx.x;          // grid = 8 * 16 * 8 = 1024
    const int b    = bid >> 7;
    const int mc   = (bid >> 3) & (MCHUNK - 1);
    const int ns   = bid & 7;
    const int tid  = threadIdx.x;
    const int lane = tid & 63;
    const int wv   = tid >> 6;
    const int r    = lane & 31;
    const int hk   = lane >> 5;

    if (bid == 0 && tid == 0) out[0] = 0.0f;   // for reduceB's atomicAdd

    const _Float16 Z = (_Float16)0.0f, ONE = (_Float16)1.0f;

    // ---- B-fragments + aa for this wave's 4 column groups ----
    const float* advb = adv + (size_t)b * KPTS * 3;
    const int m0 = mc * CBLK + wv * 128 + r;
    half8 bf0, bf1, bf2, bf3;
    float aa0, aa1, aa2, aa3;
#pragma unroll
    for (int i = 0; i < 4; ++i) {
        const int m = m0 + 32 * i;
        float ax = advb[3 * m], ay = advb[3 * m + 1], az = advb[3 * m + 2];
        float aa = ax * ax + ay * ay + az * az;
        float tx = -2.f * ax, ty = -2.f * ay, tz = -2.f * az;
        _Float16 bx = (_Float16)tx, by = (_Float16)ty, bz = (_Float16)tz;
        _Float16 cx = (_Float16)(tx - (float)bx);
        _Float16 cy = (_Float16)(ty - (float)by);
        _Float16 cz = (_Float16)(tz - (float)bz);
        half8 h0 = {bx, by, bz, cx, cy, cz, bx, by};
        half8 h1 = {bz, ONE, ONE, Z, Z, Z, Z, Z};
        half8 bi = hk ? h1 : h0;
        if (i == 0) { bf0 = bi; aa0 = aa; }
        else if (i == 1) { bf1 = bi; aa1 = aa; }
        else if (i == 2) { bf2 = bi; aa2 = aa; }
        else { bf3 = bi; aa3 = aa; }
    }

    // ---- stage + convert this block's 1024-row slice into LDS (once) ----
    const float* orib = ori + ((size_t)b * KPTS + (size_t)ns * RBLK) * 3;
#pragma unroll
    for (int i = 0; i < 4; ++i) {
        const int rr = tid + i * 256;
        const float* op = orib + (size_t)rr * 3;
        float x = op[0], y = op[1], z = op[2];
        float oo = x * x + y * y + z * z;
        _Float16 hx = (_Float16)x, hy = (_Float16)y, hz = (_Float16)z;
        _Float16 lx = (_Float16)(x - (float)hx);
        _Float16 ly = (_Float16)(y - (float)hy);
        _Float16 lz = (_Float16)(z - (float)hz);
        _Float16 oh = (_Float16)oo;
        _Float16 ol = (_Float16)(oo - (float)oh);
        half8 a0 = {hx, hy, hz, hx, hy, hz, lx, ly};
        half8 a1 = {lz, oh, ol, Z, Z, Z, Z, Z};
        const int off = ((rr >> 5) << 9) + ((rr & 31) << 3);
        *(half8*)(&sA[off])       = a0;
        *(half8*)(&sA[off + 256]) = a1;
    }
    __syncthreads();   // the only barrier

    float rm0 = __builtin_huge_valf(), rm1 = __builtin_huge_valf();
    float rm2 = __builtin_huge_valf(), rm3 = __builtin_huge_valf();

    const _Float16* apl = sA + lane * 8;   // lane's 16B within tile 0

    // ---- prologue: tile 0 into both banks; nops cover first loop fold ----
    half8 af = *(const half8*)apl;
    MFMA2_X(af, bf0, bf1);
    MFMA2_Y(af, bf2, bf3);
    asm volatile("s_nop 7\n\ts_nop 7" ::: );
    af = *(const half8*)(apl + 512);       // tile 1

    // ---- pipelined loop: fold(t-1) ∥ MFMA(t), zero nops ----
#pragma unroll 2
    for (int t = 1; t < TSLICE; ++t) {
        half8 afn = *(const half8*)(apl + (size_t)(t + 1) * 512);  // prefetch (pad at t=31)
        FOLD_X(rm0, rm1);         // d01 of t-1 (>=18 instrs after its MFMA)
        MFMA2_X(af, bf0, bf1);    // d01 of t
        FOLD_Y(rm2, rm3);         // d23 of t-1
        MFMA2_Y(af, bf2, bf3);    // d23 of t
        af = afn;
    }

    // ---- epilogue: fold tile 31 (distances >=16 instrs, in-order safe) ----
    FOLD_X(rm0, rm1);
    FOLD_Y(rm2, rm3);

    // complete the 32-row min (lanes l, l^32 cover complementary rows, same col)
    rm0 = fminf(rm0, __shfl_xor(rm0, 32, 64));
    rm1 = fminf(rm1, __shfl_xor(rm1, 32, 64));
    rm2 = fminf(rm2, __shfl_xor(rm2, 32, 64));
    rm3 = fminf(rm3, __shfl_xor(rm3, 32, 64));

    // plain coalesced partial stores part[ns][b][col] (no init required)
    float* p = part + ((size_t)ns * BATCH + b) * KPTS;
    if (hk == 0) {
        p[m0]      = fmaxf(rm0 + aa0, 0.0f);
        p[m0 + 32] = fmaxf(rm1 + aa1, 0.0f);
        p[m0 + 64] = fmaxf(rm2 + aa2, 0.0f);
        p[m0 + 96] = fmaxf(rm3 + aa3, 0.0f);
    }
}

// 8 blocks (one per batch), 1024 threads: min over slices, max over columns.
__global__ __launch_bounds__(1024) void reduceB(const float* __restrict__ part,
                                                const float* __restrict__ w,
                                                float* __restrict__ out) {
    const int b = blockIdx.x;
    const int tid = threadIdx.x;

    float mx = 0.0f;   // partials are clamped nonneg
#pragma unroll
    for (int h = 0; h < 2; ++h) {
        const int c4 = tid + h * 1024;
        float4 v[NSPLIT];
#pragma unroll
        for (int s = 0; s < NSPLIT; ++s)
            v[s] = *(const float4*)(part + ((size_t)s * BATCH + b) * KPTS + (size_t)c4 * 4);
        float4 mn = v[0];
#pragma unroll
        for (int s = 1; s < NSPLIT; ++s) {
            mn.x = fminf(mn.x, v[s].x); mn.y = fminf(mn.y, v[s].y);
            mn.z = fminf(mn.z, v[s].z); mn.w = fminf(mn.w, v[s].w);
        }
        mx = fmaxf(mx, fmaxf(fmaxf(mn.x, mn.y), fmaxf(mn.z, mn.w)));
    }

#pragma unroll
    for (int off = 32; off; off >>= 1)
        mx = fmaxf(mx, __shfl_xor(mx, off, 64));

    __shared__ float red[16];
    if ((tid & 63) == 0) red[tid >> 6] = mx;
    __syncthreads();
    if (tid == 0) {
        float m2 = red[0];
#pragma unroll
        for (int i = 1; i < 16; ++i) m2 = fmaxf(m2, red[i]);
        atomicAdd(out, m2 * w[b] * (1.0f / BATCH));
    }
}

extern "C" void kernel_launch(void* const* d_in, const int* in_sizes, int n_in,
                              void* d_out, int out_size, void* d_ws, size_t ws_size,
                              hipStream_t stream) {
    const float* adv = (const float*)d_in[0];   // [B, K, 3]
    const float* ori = (const float*)d_in[1];   // [B, K, 3]
    const float* w   = (const float*)d_in[2];   // [B]
    float* out = (float*)d_out;
    float* part = (float*)d_ws;                 // NSPLIT*B*K floats = 2 MB

    hausdorff<<<BATCH * MCHUNK * NSPLIT, 256, 0, stream>>>(adv, ori, part, out);
    reduceB<<<BATCH, 1024, 0, stream>>>((const float*)part, w, out);
}

// Round 15
// 76.175 us; speedup vs baseline: 1.0142x; 1.0142x over previous
//
#include <hip/hip_runtime.h>

// Hausdorff adv2ori via MFMA: B=8, K=8192.  FINAL (= R13, measured 74.7us).
// dist(n,m) = oo_n + aa_m - 2*o.a ; C = mfma(A',B') = oo_n - 2*o.a (fp16 hi/lo split)
// loss = mean_b( w_b * max_m min_n dist )
//
// R14 post-mortem: dual-bank zero-nop pipeline regressed (77.3 vs 74.7) —
// third falsification of fold||MFMA overlap (R11~0, R12~0, R14 -2.5us): at 16
// waves/CU cross-wave TLP already hides the MFMA->VALU hazard; extra asm
// blocks only add scheduling constraints. Reverting to the measured best.
//
// Session accounting (final): total ~75us = 40.5us harness workspace re-poison
// fill (268MB, in-stream, unavoidable) + ~5us launch/gaps/reduceB + ~29us main
// (~18.7us warm steady-state [R9 8x-rep] + ~11us post-fill cold-clock window,
// invariant across 7 structural rewrites). Warm state: MfmaUtil 42%,
// VALUBusy 59%, conflicts 0, no spills — both pipes co-loaded within ~2x of
// the issue model. Controllable levers exhausted.

#define KPTS 8192
#define BATCH 8
#define NSPLIT 8
#define RBLK (KPTS / NSPLIT)          // 1024 rows per slice
#define TSLICE (RBLK / 32)            // 32 MFMA row-tiles per slice
#define CBLK 512                      // adv columns per block (4 waves x 128)
#define MCHUNK (KPTS / CBLK)          // 16

typedef _Float16 half8 __attribute__((ext_vector_type(8)));

// One tile: 4 MFMAs into pinned v[64:127] (C = inline 0), hazard nops, then
// in-place min3 folds (d is dead after; next tile's MFMAs rewrite it).
// rm0..rm3 are "+v" scalars. No f32x16 ever crosses an asm boundary.
#define TILE_ASM(af_, rm0_, rm1_, rm2_, rm3_, b0_, b1_, b2_, b3_)             \
    asm volatile(                                                             \
        "v_mfma_f32_32x32x16_f16 v[64:79], %4, %5, 0\n\t"                     \
        "v_mfma_f32_32x32x16_f16 v[80:95], %4, %6, 0\n\t"                     \
        "v_mfma_f32_32x32x16_f16 v[96:111], %4, %7, 0\n\t"                    \
        "v_mfma_f32_32x32x16_f16 v[112:127], %4, %8, 0\n\t"                   \
        "s_nop 7\n\t"                                                         \
        "s_nop 7\n\t"                                                         \
        "v_min3_f32 v64, v64, v65, v66\n\t"                                   \
        "v_min3_f32 v67, v67, v68, v69\n\t"                                   \
        "v_min3_f32 v70, v70, v71, v72\n\t"                                   \
        "v_min3_f32 v73, v73, v74, v75\n\t"                                   \
        "v_min3_f32 v76, v76, v77, v78\n\t"                                   \
        "v_min3_f32 v79, v79, %0, v64\n\t"                                    \
        "v_min3_f32 v67, v67, v70, v73\n\t"                                   \
        "v_min3_f32 %0, v76, v79, v67\n\t"                                    \
        "v_min3_f32 v80, v80, v81, v82\n\t"                                   \
        "v_min3_f32 v83, v83, v84, v85\n\t"                                   \
        "v_min3_f32 v86, v86, v87, v88\n\t"                                   \
        "v_min3_f32 v89, v89, v90, v91\n\t"                                   \
        "v_min3_f32 v92, v92, v93, v94\n\t"                                   \
        "v_min3_f32 v95, v95, %1, v80\n\t"                                    \
        "v_min3_f32 v83, v83, v86, v89\n\t"                                   \
        "v_min3_f32 %1, v92, v95, v83\n\t"                                    \
        "v_min3_f32 v96, v96, v97, v98\n\t"                                   \
        "v_min3_f32 v99, v99, v100, v101\n\t"                                 \
        "v_min3_f32 v102, v102, v103, v104\n\t"                               \
        "v_min3_f32 v105, v105, v106, v107\n\t"                               \
        "v_min3_f32 v108, v108, v109, v110\n\t"                               \
        "v_min3_f32 v111, v111, %2, v96\n\t"                                  \
        "v_min3_f32 v99, v99, v102, v105\n\t"                                 \
        "v_min3_f32 %2, v108, v111, v99\n\t"                                  \
        "v_min3_f32 v112, v112, v113, v114\n\t"                               \
        "v_min3_f32 v115, v115, v116, v117\n\t"                               \
        "v_min3_f32 v118, v118, v119, v120\n\t"                               \
        "v_min3_f32 v121, v121, v122, v123\n\t"                               \
        "v_min3_f32 v124, v124, v125, v126\n\t"                               \
        "v_min3_f32 v127, v127, %3, v112\n\t"                                 \
        "v_min3_f32 v115, v115, v118, v121\n\t"                               \
        "v_min3_f32 %3, v124, v127, v115"                                     \
        : "+v"(rm0_), "+v"(rm1_), "+v"(rm2_), "+v"(rm3_)                      \
        : "v"(af_), "v"(b0_), "v"(b1_), "v"(b2_), "v"(b3_)                    \
        : "v64","v65","v66","v67","v68","v69","v70","v71",                    \
          "v72","v73","v74","v75","v76","v77","v78","v79",                    \
          "v80","v81","v82","v83","v84","v85","v86","v87",                    \
          "v88","v89","v90","v91","v92","v93","v94","v95",                    \
          "v96","v97","v98","v99","v100","v101","v102","v103",                \
          "v104","v105","v106","v107","v108","v109","v110","v111",            \
          "v112","v113","v114","v115","v116","v117","v118","v119",            \
          "v120","v121","v122","v123","v124","v125","v126","v127")

__global__ __launch_bounds__(256, 4) void hausdorff(const float* __restrict__ adv,
                                                    const float* __restrict__ ori,
                                                    float* __restrict__ part,
                                                    float* __restrict__ out) {
    // Tile-planar A' slice: tile t at halfs [t*512,(t+1)*512); lane reads
    // byte lane*16 -> linear, conflict-free. +1 pad tile for last prefetch.
    __shared__ _Float16 sA[(TSLICE + 1) * 512];   // 33 KB -> 4 blocks/CU

    const int bid  = blockIdx.x;          // grid = 8 * 16 * 8 = 1024
    const int b    = bid >> 7;
    const int mc   = (bid >> 3) & (MCHUNK - 1);
    const int ns   = bid & 7;
    const int tid  = threadIdx.x;
    const int lane = tid & 63;
    const int wv   = tid >> 6;
    const int r    = lane & 31;
    const int hk   = lane >> 5;

    if (bid == 0 && tid == 0) out[0] = 0.0f;   // for reduceB's atomicAdd

    const _Float16 Z = (_Float16)0.0f, ONE = (_Float16)1.0f;

    // ---- B-fragments + aa for this wave's 4 column groups ----
    const float* advb = adv + (size_t)b * KPTS * 3;
    const int m0 = mc * CBLK + wv * 128 + r;
    half8 bf0, bf1, bf2, bf3;
    float aa0, aa1, aa2, aa3;
#pragma unroll
    for (int i = 0; i < 4; ++i) {
        const int m = m0 + 32 * i;
        float ax = advb[3 * m], ay = advb[3 * m + 1], az = advb[3 * m + 2];
        float aa = ax * ax + ay * ay + az * az;
        float tx = -2.f * ax, ty = -2.f * ay, tz = -2.f * az;
        _Float16 bx = (_Float16)tx, by = (_Float16)ty, bz = (_Float16)tz;
        _Float16 cx = (_Float16)(tx - (float)bx);
        _Float16 cy = (_Float16)(ty - (float)by);
        _Float16 cz = (_Float16)(tz - (float)bz);
        half8 h0 = {bx, by, bz, cx, cy, cz, bx, by};
        half8 h1 = {bz, ONE, ONE, Z, Z, Z, Z, Z};
        half8 bi = hk ? h1 : h0;
        if (i == 0) { bf0 = bi; aa0 = aa; }
        else if (i == 1) { bf1 = bi; aa1 = aa; }
        else if (i == 2) { bf2 = bi; aa2 = aa; }
        else { bf3 = bi; aa3 = aa; }
    }

    // ---- stage + convert this block's 1024-row slice into LDS (once) ----
    const float* orib = ori + ((size_t)b * KPTS + (size_t)ns * RBLK) * 3;
#pragma unroll
    for (int i = 0; i < 4; ++i) {
        const int rr = tid + i * 256;
        const float* op = orib + (size_t)rr * 3;
        float x = op[0], y = op[1], z = op[2];
        float oo = x * x + y * y + z * z;
        _Float16 hx = (_Float16)x, hy = (_Float16)y, hz = (_Float16)z;
        _Float16 lx = (_Float16)(x - (float)hx);
        _Float16 ly = (_Float16)(y - (float)hy);
        _Float16 lz = (_Float16)(z - (float)hz);
        _Float16 oh = (_Float16)oo;
        _Float16 ol = (_Float16)(oo - (float)oh);
        half8 a0 = {hx, hy, hz, hx, hy, hz, lx, ly};
        half8 a1 = {lz, oh, ol, Z, Z, Z, Z, Z};
        const int off = ((rr >> 5) << 9) + ((rr & 31) << 3);
        *(half8*)(&sA[off])       = a0;
        *(half8*)(&sA[off + 256]) = a1;
    }
    __syncthreads();   // the only barrier

    float rm0 = __builtin_huge_valf(), rm1 = __builtin_huge_valf();
    float rm2 = __builtin_huge_valf(), rm3 = __builtin_huge_valf();

    const _Float16* apl = sA + lane * 8;   // lane's 16B within tile 0

    // Full-tile prefetch distance: ds_read(t+1) issued before tile t's asm;
    // consumed next iteration. Pad tile absorbs the t=31 overread.
    half8 af = *(const half8*)apl;
#pragma unroll 2
    for (int t = 0; t < TSLICE; ++t) {
        half8 afn = *(const half8*)(apl + (size_t)(t + 1) * 512);
        TILE_ASM(af, rm0, rm1, rm2, rm3, bf0, bf1, bf2, bf3);
        af = afn;
    }

    // complete the 32-row min (lanes l, l^32 cover complementary rows, same col)
    rm0 = fminf(rm0, __shfl_xor(rm0, 32, 64));
    rm1 = fminf(rm1, __shfl_xor(rm1, 32, 64));
    rm2 = fminf(rm2, __shfl_xor(rm2, 32, 64));
    rm3 = fminf(rm3, __shfl_xor(rm3, 32, 64));

    // plain coalesced partial stores part[ns][b][col] (no init required)
    float* p = part + ((size_t)ns * BATCH + b) * KPTS;
    if (hk == 0) {
        p[m0]      = fmaxf(rm0 + aa0, 0.0f);
        p[m0 + 32] = fmaxf(rm1 + aa1, 0.0f);
        p[m0 + 64] = fmaxf(rm2 + aa2, 0.0f);
        p[m0 + 96] = fmaxf(rm3 + aa3, 0.0f);
    }
}

// 8 blocks (one per batch), 1024 threads: min over slices, max over columns.
__global__ __launch_bounds__(1024) void reduceB(const float* __restrict__ part,
                                                const float* __restrict__ w,
                                                float* __restrict__ out) {
    const int b = blockIdx.x;
    const int tid = threadIdx.x;

    float mx = 0.0f;   // partials are clamped nonneg
#pragma unroll
    for (int h = 0; h < 2; ++h) {
        const int c4 = tid + h * 1024;
        float4 v[NSPLIT];
#pragma unroll
        for (int s = 0; s < NSPLIT; ++s)
            v[s] = *(const float4*)(part + ((size_t)s * BATCH + b) * KPTS + (size_t)c4 * 4);
        float4 mn = v[0];
#pragma unroll
        for (int s = 1; s < NSPLIT; ++s) {
            mn.x = fminf(mn.x, v[s].x); mn.y = fminf(mn.y, v[s].y);
            mn.z = fminf(mn.z, v[s].z); mn.w = fminf(mn.w, v[s].w);
        }
        mx = fmaxf(mx, fmaxf(fmaxf(mn.x, mn.y), fmaxf(mn.z, mn.w)));
    }

#pragma unroll
    for (int off = 32; off; off >>= 1)
        mx = fmaxf(mx, __shfl_xor(mx, off, 64));

    __shared__ float red[16];
    if ((tid & 63) == 0) red[tid >> 6] = mx;
    __syncthreads();
    if (tid == 0) {
        float m2 = red[0];
#pragma unroll
        for (int i = 1; i < 16; ++i) m2 = fmaxf(m2, red[i]);
        atomicAdd(out, m2 * w[b] * (1.0f / BATCH));
    }
}

extern "C" void kernel_launch(void* const* d_in, const int* in_sizes, int n_in,
                              void* d_out, int out_size, void* d_ws, size_t ws_size,
                              hipStream_t stream) {
    const float* adv = (const float*)d_in[0];   // [B, K, 3]
    const float* ori = (const float*)d_in[1];   // [B, K, 3]
    const float* w   = (const float*)d_in[2];   // [B]
    float* out = (float*)d_out;
    float* part = (float*)d_ws;                 // NSPLIT*B*K floats = 2 MB

    hausdorff<<<BATCH * MCHUNK * NSPLIT, 256, 0, stream>>>(adv, ori, part, out);
    reduceB<<<BATCH, 1024, 0, stream>>>((const float*)part, w, out);
}